// Round 1
// baseline (349.384 us; speedup 1.0000x reference)
//
#include <hip/hip_runtime.h>
#include <cmath>

#define B_ 8
#define C_ 64
#define M_ 256
#define N_ 256
#define PLANE_ (M_*N_)          // 65536
#define PIX_ (B_*PLANE_)        // 524288
#define THRESH_ 0.8f
#define EPS_ 1e-5f

// ---------------- K1: per-pixel channel avg & max (vectorized x4) ----------------
__global__ void k_avgmax(const float* __restrict__ x,
                         float* __restrict__ avgp, float* __restrict__ maxp) {
    int idx4 = (blockIdx.x * blockDim.x + threadIdx.x) * 4;   // pixel index (global, B*M*N)
    int b = idx4 >> 16;                // / PLANE_
    int p = idx4 & (PLANE_ - 1);
    const float* xb = x + (size_t)b * C_ * PLANE_ + p;
    float4 s = make_float4(0.f, 0.f, 0.f, 0.f);
    float4 mx = make_float4(-INFINITY, -INFINITY, -INFINITY, -INFINITY);
    #pragma unroll 8
    for (int c = 0; c < C_; ++c) {
        float4 v = *(const float4*)(xb + (size_t)c * PLANE_);
        s.x += v.x; s.y += v.y; s.z += v.z; s.w += v.w;
        mx.x = fmaxf(mx.x, v.x); mx.y = fmaxf(mx.y, v.y);
        mx.z = fmaxf(mx.z, v.z); mx.w = fmaxf(mx.w, v.w);
    }
    const float r = 1.f / C_;
    s.x *= r; s.y *= r; s.z *= r; s.w *= r;
    *(float4*)(avgp + idx4) = s;
    *(float4*)(maxp + idx4) = mx;
}

// ---------------- K2: 7x7 conv (2ch -> 1) + sigmoid -> sa_map ----------------
__global__ void k_saconv(const float* __restrict__ avgp, const float* __restrict__ maxp,
                         const float* __restrict__ w1, float* __restrict__ samap) {
    __shared__ float w[98];
    if (threadIdx.x < 98) w[threadIdx.x] = w1[threadIdx.x];
    __syncthreads();
    int idx = blockIdx.x * blockDim.x + threadIdx.x;   // global pixel
    int b = idx >> 16;
    int r = idx & (PLANE_ - 1);
    int i = r >> 8;          // / N_
    int j = r & (N_ - 1);
    const float* a = avgp + (size_t)b * PLANE_;
    const float* m = maxp + (size_t)b * PLANE_;
    float acc = 0.f;
    #pragma unroll
    for (int dh = 0; dh < 7; ++dh) {
        int ii = i + dh - 3;
        if ((unsigned)ii >= (unsigned)M_) continue;
        #pragma unroll
        for (int dw = 0; dw < 7; ++dw) {
            int jj = j + dw - 3;
            if ((unsigned)jj >= (unsigned)N_) continue;
            int o = ii * N_ + jj;
            acc += a[o] * w[dh * 7 + dw] + m[o] * w[49 + dh * 7 + dw];
        }
    }
    samap[idx] = 1.f / (1.f + expf(-acc));
}

// ------- K2b: gamma/beta 7x7 convs on sa_map, mask byte, mask count ----------
__global__ void k_gammabeta(const float* __restrict__ samap,
                            const float* __restrict__ wg, const float* __restrict__ bgp,
                            const float* __restrict__ wb, const float* __restrict__ bbp,
                            float* __restrict__ gammap, float* __restrict__ betap,
                            unsigned char* __restrict__ maskp, int* __restrict__ cntp) {
    __shared__ float w[98];
    if (threadIdx.x < 49) w[threadIdx.x] = wg[threadIdx.x];
    else if (threadIdx.x < 98) w[threadIdx.x] = wb[threadIdx.x - 49];
    __syncthreads();
    int idx = blockIdx.x * blockDim.x + threadIdx.x;
    int b = idx >> 16;
    int r = idx & (PLANE_ - 1);
    int i = r >> 8;
    int j = r & (N_ - 1);
    const float* s = samap + (size_t)b * PLANE_;
    float g = 0.f, be = 0.f;
    #pragma unroll
    for (int dh = 0; dh < 7; ++dh) {
        int ii = i + dh - 3;
        if ((unsigned)ii >= (unsigned)M_) continue;
        #pragma unroll
        for (int dw = 0; dw < 7; ++dw) {
            int jj = j + dw - 3;
            if ((unsigned)jj >= (unsigned)N_) continue;
            float v = s[ii * N_ + jj];
            g  += v * w[dh * 7 + dw];
            be += v * w[49 + dh * 7 + dw];
        }
    }
    gammap[idx] = g + bgp[0];
    betap[idx]  = be + bbp[0];
    int mk = (samap[idx] >= THRESH_) ? 1 : 0;
    maskp[idx] = (unsigned char)mk;
    // count masked pixels: ballot per wave, one atomic per block
    unsigned long long bal = __ballot(mk);
    __shared__ int wcnt[4];
    int wave = threadIdx.x >> 6, lane = threadIdx.x & 63;
    if (lane == 0) wcnt[wave] = __popcll(bal);
    __syncthreads();
    if (threadIdx.x == 0) {
        atomicAdd(cntp, wcnt[0] + wcnt[1] + wcnt[2] + wcnt[3]);
    }
}

// -------- K3: per-channel sums: S, Q, S1(masked), Q1(masked) ----------
__global__ void k_sums(const float* __restrict__ x, const unsigned char* __restrict__ maskp,
                       float* __restrict__ S, float* __restrict__ Q,
                       float* __restrict__ S1, float* __restrict__ Q1) {
    int chunk = blockIdx.x;          // 8 chunks of 8192 per plane
    int c = blockIdx.y;
    int b = blockIdx.z;
    const float* xp = x + ((size_t)(b * C_ + c)) * PLANE_ + chunk * 8192;
    const unsigned char* mp = maskp + (size_t)b * PLANE_ + chunk * 8192;
    float s = 0.f, q = 0.f, s1 = 0.f, q1 = 0.f;
    #pragma unroll
    for (int k = 0; k < 8; ++k) {
        int t = (k * 256 + threadIdx.x) * 4;
        float4 v = *(const float4*)(xp + t);
        uchar4 mm = *(const uchar4*)(mp + t);
        float m0 = (float)mm.x, m1 = (float)mm.y, m2 = (float)mm.z, m3 = (float)mm.w;
        s  += v.x + v.y + v.z + v.w;
        q  += v.x * v.x + v.y * v.y + v.z * v.z + v.w * v.w;
        s1 += v.x * m0 + v.y * m1 + v.z * m2 + v.w * m3;
        q1 += v.x * v.x * m0 + v.y * v.y * m1 + v.z * v.z * m2 + v.w * v.w * m3;
    }
    // wave reduce (64 lanes)
    for (int off = 32; off > 0; off >>= 1) {
        s  += __shfl_down(s, off, 64);
        q  += __shfl_down(q, off, 64);
        s1 += __shfl_down(s1, off, 64);
        q1 += __shfl_down(q1, off, 64);
    }
    __shared__ float ls[4][4];
    int wave = threadIdx.x >> 6, lane = threadIdx.x & 63;
    if (lane == 0) { ls[wave][0] = s; ls[wave][1] = q; ls[wave][2] = s1; ls[wave][3] = q1; }
    __syncthreads();
    if (threadIdx.x == 0) {
        float ts = 0.f, tq = 0.f, ts1 = 0.f, tq1 = 0.f;
        #pragma unroll
        for (int wv = 0; wv < 4; ++wv) { ts += ls[wv][0]; tq += ls[wv][1]; ts1 += ls[wv][2]; tq1 += ls[wv][3]; }
        atomicAdd(&S[c], ts); atomicAdd(&Q[c], tq);
        atomicAdd(&S1[c], ts1); atomicAdd(&Q1[c], tq1);
    }
}

// -------- K4: fold sums into per-channel affine coefficients ----------
__global__ void k_coef(const float* __restrict__ S, const float* __restrict__ Q,
                       const float* __restrict__ S1, const float* __restrict__ Q1,
                       const int* __restrict__ cntp,
                       float* __restrict__ cMa, float* __restrict__ cMb,
                       float* __restrict__ cUa, float* __restrict__ cUb) {
    int c = threadIdx.x;
    if (c >= C_) return;
    const float P = (float)PIX_;
    int cnt1 = *cntp;
    float fc1 = (float)cnt1;
    float fc0 = P - fc1;
    float Sr1 = (cnt1 == 0) ? 1.f : fc1;
    float Sr0 = (cnt1 == PIX_) ? 1.f : fc0;
    float Sv = S[c], Qv = Q[c], S1v = S1[c], Q1v = Q1[c];
    float S0v = Sv - S1v, Q0v = Qv - Q1v;
    float mu1 = S1v / Sr1;
    float mu0 = S0v / Sr0;
    // region 1 (masked): fill count = P - cnt1
    float m1 = (S1v + fc0 * mu1) / P;
    float v1 = fmaxf((Q1v + fc0 * mu1 * mu1) / P - m1 * m1, 0.f);
    // region 0 (unmasked): fill count = cnt1
    float m0 = (S0v + fc1 * mu0) / P;
    float v0 = fmaxf((Q0v + fc1 * mu0 * mu0) / P - m0 * m0, 0.f);
    float A1 = rsqrtf(v1 + EPS_) * sqrtf(Sr1 / P);
    float A0 = rsqrtf(v0 + EPS_) * sqrtf(Sr0 / P);
    float B1 = (mu1 - m1) * A1;     // region-1 contribution at unmasked pixels
    float B0 = (mu0 - m0) * A0;     // region-0 contribution at masked pixels
    cMa[c] = A1;             cMb[c] = -m1 * A1 + B0;   // masked:   x*A1 - m1*A1 + B0
    cUa[c] = A0;             cUb[c] = -m0 * A0 + B1;   // unmasked: x*A0 - m0*A0 + B1
}

// -------- K5: final elementwise: out = (x*a+b)*(1+gamma)+beta ----------
__global__ void k_final(const float* __restrict__ x, const unsigned char* __restrict__ maskp,
                        const float* __restrict__ gammap, const float* __restrict__ betap,
                        const float* __restrict__ cMa, const float* __restrict__ cMb,
                        const float* __restrict__ cUa, const float* __restrict__ cUb,
                        float* __restrict__ out) {
    int c = blockIdx.y;
    int b = blockIdx.z;
    int p0 = blockIdx.x * 1024 + threadIdx.x * 4;     // pixel within plane
    size_t base = ((size_t)(b * C_ + c)) * PLANE_ + p0;
    int pp = b * PLANE_ + p0;
    float4 xv = *(const float4*)(x + base);
    float4 gv = *(const float4*)(gammap + pp);
    float4 bv = *(const float4*)(betap + pp);
    uchar4 mv = *(const uchar4*)(maskp + pp);
    float ma = cMa[c], mb = cMb[c], ua = cUa[c], ub = cUb[c];
    float4 o;
    o.x = (mv.x ? xv.x * ma + mb : xv.x * ua + ub) * (1.f + gv.x) + bv.x;
    o.y = (mv.y ? xv.y * ma + mb : xv.y * ua + ub) * (1.f + gv.y) + bv.y;
    o.z = (mv.z ? xv.z * ma + mb : xv.z * ua + ub) * (1.f + gv.z) + bv.z;
    o.w = (mv.w ? xv.w * ma + mb : xv.w * ua + ub) * (1.f + gv.w) + bv.w;
    *(float4*)(out + base) = o;
}

extern "C" void kernel_launch(void* const* d_in, const int* in_sizes, int n_in,
                              void* d_out, int out_size, void* d_ws, size_t ws_size,
                              hipStream_t stream) {
    const float* x  = (const float*)d_in[0];
    const float* w1 = (const float*)d_in[1];
    const float* wg = (const float*)d_in[2];
    const float* bg = (const float*)d_in[3];
    const float* wb = (const float*)d_in[4];
    const float* bb = (const float*)d_in[5];
    float* out = (float*)d_out;

    float* ws = (float*)d_ws;
    float* avgp   = ws;                       // 524288
    float* maxp   = avgp + PIX_;              // 524288
    float* samap  = maxp + PIX_;              // 524288
    float* gammap = samap + PIX_;             // 524288
    float* betap  = gammap + PIX_;            // 524288
    float* S   = betap + PIX_;                // 64
    float* Q   = S + C_;                      // 64
    float* S1  = Q + C_;                      // 64
    float* Q1  = S1 + C_;                     // 64
    int*   cnt = (int*)(Q1 + C_);             // 1
    float* cMa = (float*)(cnt + 1);           // 64
    float* cMb = cMa + C_;                    // 64
    float* cUa = cMb + C_;                    // 64
    float* cUb = cUa + C_;                    // 64
    unsigned char* maskp = (unsigned char*)(cUb + C_);  // 524288 bytes

    // zero the accumulators (S,Q,S1,Q1,cnt)
    hipMemsetAsync(S, 0, (4 * C_ + 1) * sizeof(float), stream);

    // K1: channel avg/max
    k_avgmax<<<PIX_ / (256 * 4), 256, 0, stream>>>(x, avgp, maxp);
    // K2: sa_map
    k_saconv<<<PIX_ / 256, 256, 0, stream>>>(avgp, maxp, w1, samap);
    // K2b: gamma, beta, mask, count
    k_gammabeta<<<PIX_ / 256, 256, 0, stream>>>(samap, wg, bg, wb, bb,
                                                gammap, betap, maskp, cnt);
    // K3: per-channel sums
    dim3 g3(8, C_, B_);
    k_sums<<<g3, 256, 0, stream>>>(x, maskp, S, Q, S1, Q1);
    // K4: coefficients
    k_coef<<<1, 64, 0, stream>>>(S, Q, S1, Q1, cnt, cMa, cMb, cUa, cUb);
    // K5: final
    dim3 g5(PLANE_ / 1024, C_, B_);
    k_final<<<g5, 256, 0, stream>>>(x, maskp, gammap, betap, cMa, cMb, cUa, cUb, out);
}